// Round 19
// baseline (94.526 us; speedup 1.0000x reference)
//
#include <hip/hip_runtime.h>

typedef __bf16 bf16x8 __attribute__((ext_vector_type(8)));
typedef float f32x4 __attribute__((ext_vector_type(4)));

__device__ __forceinline__ unsigned short f2bf(float f) {
  union { float f; unsigned u; } x; x.f = f;
  unsigned r = x.u + 0x7FFFu + ((x.u >> 16) & 1u);
  return (unsigned short)(r >> 16);
}

// raw v_exp_f32 (2^x) — skips libm's denormal-guard sequence; inputs bounded here.
__device__ __forceinline__ float fast_exp2(float x) {
  float r;
  asm("v_exp_f32 %0, %1" : "=v"(r) : "v"(x));
  return r;
}

// async global->LDS, 16B per lane; LDS dest must be linear (base + lane*16).
__device__ __forceinline__ void gload_lds16(const void* g, void* l) {
  __builtin_amdgcn_global_load_lds(
      (const __attribute__((address_space(1))) unsigned int*)g,
      (__attribute__((address_space(3))) unsigned int*)l, 16, 0, 0);
}

__device__ __forceinline__ f32x4 mfma16(bf16x8 a, bf16x8 b, f32x4 c) {
  return __builtin_amdgcn_mfma_f32_16x16x32_bf16(a, b, c, 0, 0, 0);
}

__device__ __forceinline__ bf16x8 pack8(const f32x4& a, const f32x4& b) {
  bf16x8 r;
  r[0] = (__bf16)a[0]; r[1] = (__bf16)a[1]; r[2] = (__bf16)a[2]; r[3] = (__bf16)a[3];
  r[4] = (__bf16)b[0]; r[5] = (__bf16)b[1]; r[6] = (__bf16)b[2]; r[7] = (__bf16)b[3];
  return r;
}

// ---------------- fused conversions: y<3 -> q/k/v f32->bf16; y==3 -> W transpose ----------------
// Kept as a separate pass: fusing the A-conversion into gemm_qkv (r17) raised FETCH 24->72MB
// (f32 A re-read 6x no longer L2-fits) and dropped occupancy to 12% — 57MB once is cheaper.
__global__ __launch_bounds__(256) void conv_all(const float* __restrict__ q,
                                                const float* __restrict__ k,
                                                const float* __restrict__ v,
                                                const float* __restrict__ W0,
                                                const float* __restrict__ W1,
                                                const float* __restrict__ W2,
                                                const float* __restrict__ W3,
                                                unsigned short* __restrict__ dst,
                                                unsigned short* __restrict__ Wt) {
  __shared__ float tile[32][33];
  if (blockIdx.y < 3) {
    const float* src = (blockIdx.y == 0) ? q : (blockIdx.y == 1 ? k : v);
    size_t i = ((size_t)blockIdx.x * 256 + threadIdx.x) * 4;
    float4 f = *(const float4*)(src + i);
    ushort4 u;
    u.x = f2bf(f.x); u.y = f2bf(f.y); u.z = f2bf(f.z); u.w = f2bf(f.w);
    *(ushort4*)(dst + (size_t)blockIdx.y * (4096u * 768u) + i) = u;
  } else {
    if (blockIdx.x >= 2304) return;   // 24*24*4 W-transpose blocks
    int idx = blockIdx.x;
    int bx = idx % 24, by = (idx / 24) % 24, bz = idx / 576;
    const float* W = (bz == 0) ? W0 : (bz == 1) ? W1 : (bz == 2) ? W2 : W3;
    int tx = threadIdx.x & 31, ty = threadIdx.x >> 5;  // 32 x 8
    int n0 = bx * 32, k0 = by * 32;
#pragma unroll
    for (int i = 0; i < 4; ++i)
      tile[ty * 4 + i][tx] = W[(size_t)(k0 + ty * 4 + i) * 768 + n0 + tx];
    __syncthreads();
    unsigned short* o = Wt + (size_t)bz * 768 * 768;
#pragma unroll
    for (int i = 0; i < 4; ++i)
      o[(size_t)(n0 + ty * 4 + i) * 768 + k0 + tx] = f2bf(tile[tx][ty * 4 + i]);
  }
}

// ---------------- QKV projections: 128x128 tile, 4 waves, dbuf BK=64 ----------------
// (z=0 qh*SCALE*log2e, z=1 kh, z=2 vh-transposed)
// flat grid, m-fastest within XCD chunks: B panel stays L2-resident per XCD.
__global__ __launch_bounds__(256) void gemm_qkv(const unsigned short* __restrict__ Abase,
                                                const unsigned short* __restrict__ Wt,
                                                unsigned short* __restrict__ Hq,
                                                unsigned short* __restrict__ Hk,
                                                unsigned short* __restrict__ Hvt) {
  __shared__ unsigned short As[2][128 * 64], Bs[2][128 * 64];  // 64 KB
  const int flat = blockIdx.x;                    // 576 blocks
  const int lid = (flat & 7) * 72 + (flat >> 3);  // XCD k gets lid [k*72,(k+1)*72)
  const int z = lid / 192;
  const int rem = lid - z * 192;
  const int m0 = (rem & 31) * 128;                // m fastest within chunk
  const int n0 = (rem >> 5) * 128;
  const unsigned short* A = Abase + (size_t)z * 4096 * 768;
  const unsigned short* B = Wt + (size_t)z * 768 * 768;
  const int t = threadIdx.x, l = t & 63, wid = t >> 6;
  const int g = l >> 4, c16 = l & 15;
  const int wm = (wid >> 1) * 64, wn = (wid & 1) * 64;

  auto stage = [&](unsigned short* dst, const unsigned short* src, int base, int k0) {
#pragma unroll
    for (int i = 0; i < 4; ++i) {
      int fc = i * 256 + t, r = fc >> 3, c = (fc & 7) ^ ((r >> 1) & 7);
      gload_lds16(src + (size_t)(base + r) * 768 + k0 + c * 8, (char*)dst + fc * 16);
    }
  };
  stage(As[0], A, m0, 0);
  stage(Bs[0], B, n0, 0);
  asm volatile("s_waitcnt vmcnt(0)" ::: "memory");
  __syncthreads();
  f32x4 acc[4][4] = {};
  for (int s = 0; s < 12; ++s) {
    const int cur = s & 1;
    if (s < 11) {
      stage(As[cur ^ 1], A, m0, (s + 1) * 64);
      stage(Bs[cur ^ 1], B, n0, (s + 1) * 64);
    }
#pragma unroll
    for (int kk = 0; kk < 2; ++kk) {
      const int ch = kk * 4 + g;
      bf16x8 a[4], bw[4];
#pragma unroll
      for (int mi = 0; mi < 4; ++mi) {
        int r = wm + mi * 16 + c16;
        a[mi] = *(const bf16x8*)((char*)As[cur] + r * 128 + (((ch ^ (r >> 1)) & 7) << 4));
      }
#pragma unroll
      for (int ni = 0; ni < 4; ++ni) {
        int r = wn + ni * 16 + c16;
        bw[ni] = *(const bf16x8*)((char*)Bs[cur] + r * 128 + (((ch ^ (r >> 1)) & 7) << 4));
      }
#pragma unroll
      for (int mi = 0; mi < 4; ++mi)
#pragma unroll
        for (int ni = 0; ni < 4; ++ni)
          acc[mi][ni] = mfma16(a[mi], bw[ni], acc[mi][ni]);
    }
    __syncthreads();
  }

  if (z < 2) {
    // fold SCALE*log2(e) into q so attn uses exp2 directly
    const float f = (z == 0) ? 0.125f * 1.44269504088896341f : 1.0f;
    unsigned short* C = (z == 0) ? Hq : Hk;
#pragma unroll
    for (int mi = 0; mi < 4; ++mi)
#pragma unroll
      for (int ni = 0; ni < 4; ++ni) {
        int col = n0 + wn + ni * 16 + c16;
        int row = m0 + wm + mi * 16 + g * 4;
#pragma unroll
        for (int j = 0; j < 4; ++j)
          C[(size_t)(row + j) * 768 + col] = f2bf(acc[mi][ni][j] * f);
      }
  } else {
    // vhT[(b*768 + col)*1024 + m] : head-major rows, sequence contiguous
#pragma unroll
    for (int mi = 0; mi < 4; ++mi) {
      int rowbase = m0 + wm + mi * 16;  // 128-tile never crosses the 1024 batch bound
      int bat = rowbase >> 10;
      int mloc = (rowbase & 1023) + g * 4;
#pragma unroll
      for (int ni = 0; ni < 4; ++ni) {
        int col = n0 + wn + ni * 16 + c16;
        ushort4 u;
        u.x = f2bf(acc[mi][ni][0]); u.y = f2bf(acc[mi][ni][1]);
        u.z = f2bf(acc[mi][ni][2]); u.w = f2bf(acc[mi][ni][3]);
        *(ushort4*)(Hvt + (((size_t)(bat * 768 + col)) << 10) + mloc) = u;
      }
    }
  }
}

// ---------------- fused attention: frozen structure + T5 s_setprio around MFMA ----------------
// Falsified alternatives (all regressed): deeper prefetch (r6/r7/r9), full unroll (r10),
// no-LDS streaming (r8), KVBLK=128 (r13), kv-split x2 (r15), fused f32 staging (r17).
// T5 rationale: ~2-3 independent blocks/CU at unsynchronized phases -> raising priority
// during MFMA clusters biases issue toward matrix-feeding waves (m191 regime, attn +4-7%).
// K LDS position p holds global kv row sigma(p) = 32*(p>>5) + 8*((p>>2)&3) + 4*((p>>4)&1) + (p&3).
// After mfma(K,Q): lane (g,c16) p[ni][j] = S[q=c16][kv = 32*(ni>>1)+8g+4*(ni&1)+j] ->
// post-softmax values ARE the PV A-fragments. No P LDS round-trip.
__global__ __launch_bounds__(256) void attn(const unsigned short* __restrict__ qh,
                                            const unsigned short* __restrict__ kh,
                                            const unsigned short* __restrict__ vhT,
                                            const float* __restrict__ mask,
                                            unsigned short* __restrict__ xb) {
  __shared__ unsigned short Ks[3][64 * 64], Vts[3][64 * 64];
  // h-fastest order + XCD-chunk swizzle: XCD k gets one batch's K/V (L2-fits) and
  // co-residents the 12 h-blocks sharing each mask tile.
  const int flat = blockIdx.x;                    // 768 blocks
  const int lid = (flat & 7) * 96 + (flat >> 3);  // dispatch i -> XCD i%8
  const int h = lid % 12, qt = (lid / 12) & 15, b = lid / 192;
  const int t = threadIdx.x, l = t & 63, wid = t >> 6;
  const int g = l >> 4, c16 = l & 15;

  // Q B-fragments straight to registers (q-col = qt*64+wid*16+c16, chans kk*32+g*8..+8)
  const unsigned short* qp =
      qh + ((size_t)(b * 1024 + qt * 64 + wid * 16 + c16)) * 768 + h * 64 + g * 8;
  bf16x8 aq0 = *(const bf16x8*)qp;
  bf16x8 aq1 = *(const bf16x8*)(qp + 32);

  // per-lane staging source pointers; K rows sigma-permuted, V linear
  const int fc0 = t, r0 = fc0 >> 3, c0 = (fc0 & 7) ^ ((r0 >> 1) & 7);
  const int fc1 = 256 + t, r1 = fc1 >> 3, c1 = (fc1 & 7) ^ ((r1 >> 1) & 7);
  const int s0 = 32 * (r0 >> 5) + 8 * ((r0 >> 2) & 3) + 4 * ((r0 >> 4) & 1) + (r0 & 3);
  const int s1 = 32 * (r1 >> 5) + 8 * ((r1 >> 2) & 3) + 4 * ((r1 >> 4) & 1) + (r1 & 3);
  const unsigned short* kp0 = kh + (size_t)(b * 1024 + s0) * 768 + h * 64 + c0 * 8;
  const unsigned short* kp1 = kh + (size_t)(b * 1024 + s1) * 768 + h * 64 + c1 * 8;
  const unsigned short* vp0 = vhT + ((size_t)(b * 768 + h * 64 + r0)) * 1024 + c0 * 8;
  const unsigned short* vp1 = vhT + ((size_t)(b * 768 + h * 64 + r1)) * 1024 + c1 * 8;

  auto stageKV = [&](int buf) {
    char* kd = (char*)Ks[buf];
    char* vd = (char*)Vts[buf];
    gload_lds16(kp0, kd + fc0 * 16);
    gload_lds16(kp1, kd + fc1 * 16);
    gload_lds16(vp0, vd + fc0 * 16);
    gload_lds16(vp1, vd + fc1 * 16);
    kp0 += 64 * 768; kp1 += 64 * 768; vp0 += 64; vp1 += 64;
  };

  // mask row base: q-row = c16 (swapped layout), 4-contiguous kv per lane -> float4
  const float* mq = mask + ((size_t)(b * 1024 + qt * 64 + wid * 16 + c16)) * 1024 + 8 * g;

  // prologue: 2 tiles in flight, wait only tile 0
  stageKV(0);
  stageKV(1);
  asm volatile("s_waitcnt vmcnt(4)" ::: "memory");
  __builtin_amdgcn_s_barrier();

  f32x4 o[4] = {};
  f32x4 ls = {0.f, 0.f, 0.f, 0.f};

  for (int kv = 0; kv < 16; ++kv) {
    const int cur = kv % 3;
    if (kv < 14) stageKV((kv + 2) % 3);  // 2-deep prefetch
    // mask tile -> registers, vectorized (latency hides under QK^T)
    const float* mk = mq + kv * 64;
    f32x4 mreg[4];
    mreg[0] = *(const f32x4*)(mk);
    mreg[1] = *(const f32x4*)(mk + 4);
    mreg[2] = *(const f32x4*)(mk + 32);
    mreg[3] = *(const f32x4*)(mk + 36);
    // S^T tiles: mfma(A=K, B=Q) -> lane holds q-row c16
    f32x4 p[4] = {};
    __builtin_amdgcn_s_setprio(1);
#pragma unroll
    for (int kk = 0; kk < 2; ++kk) {
      const int ch = kk * 4 + g;
      bf16x8 aq = kk ? aq1 : aq0;
#pragma unroll
      for (int ni = 0; ni < 4; ++ni) {
        int r = ni * 16 + c16;
        bf16x8 bk = *(const bf16x8*)((char*)Ks[cur] + r * 128 + (((ch ^ (r >> 1)) & 7) << 4));
        p[ni] = mfma16(bk, aq, p[ni]);
      }
    }
    __builtin_amdgcn_s_setprio(0);
    // exp2 via raw v_exp_f32 (q pre-scaled), lane-local row-sum, post-softmax mask
#pragma unroll
    for (int ni = 0; ni < 4; ++ni) {
      float e0 = fast_exp2(p[ni][0]);
      float e1 = fast_exp2(p[ni][1]);
      float e2 = fast_exp2(p[ni][2]);
      float e3 = fast_exp2(p[ni][3]);
      ls[ni] += (e0 + e1) + (e2 + e3);
      p[ni][0] = e0 * mreg[ni][0];
      p[ni][1] = e1 * mreg[ni][1];
      p[ni][2] = e2 * mreg[ni][2];
      p[ni][3] = e3 * mreg[ni][3];
    }
    // P is already in PV A-fragment layout: pack to bf16 and multiply
    bf16x8 pa0 = pack8(p[0], p[1]);  // kv 8g..8g+7
    bf16x8 pa1 = pack8(p[2], p[3]);  // kv 32+8g..+7
    __builtin_amdgcn_s_setprio(1);
#pragma unroll
    for (int kk = 0; kk < 2; ++kk) {
      const int ch = kk * 4 + g;
      bf16x8 ap = kk ? pa1 : pa0;
#pragma unroll
      for (int ni = 0; ni < 4; ++ni) {
        int r = ni * 16 + c16;
        bf16x8 bv = *(const bf16x8*)((char*)Vts[cur] + r * 128 + (((ch ^ (r >> 1)) & 7) << 4));
        o[ni] = mfma16(ap, bv, o[ni]);
      }
    }
    __builtin_amdgcn_s_setprio(0);
    // counted wait: tile kv+1 landed, tile kv+2 may stay in flight (never drain to 0)
    if (kv < 14) {
      asm volatile("s_waitcnt vmcnt(4)" ::: "memory");
      __builtin_amdgcn_s_barrier();
    } else if (kv == 14) {
      asm volatile("s_waitcnt vmcnt(0)" ::: "memory");
      __builtin_amdgcn_s_barrier();
    }
  }
  // full row-sum for q-row c16 lives across lanes c16, c16+16, c16+32, c16+48
  float s = (ls[0] + ls[1]) + (ls[2] + ls[3]);
  s += __shfl_xor(s, 16);
  s += __shfl_xor(s, 32);
  float rinv = 1.0f / s;
  // o rows are q = g*4+j -> fetch that row's rinv (held at lanes with lane&15 == row)
  const int rb = (l & 48) | ((l >> 2) & 12);
  float rj[4];
#pragma unroll
  for (int j = 0; j < 4; ++j) rj[j] = __shfl(rinv, rb + j);
#pragma unroll
  for (int ni = 0; ni < 4; ++ni) {
    int col = h * 64 + ni * 16 + c16;
    int row = qt * 64 + wid * 16 + g * 4;
#pragma unroll
    for (int j = 0; j < 4; ++j)
      xb[((size_t)(b * 1024) + row + j) * 768 + col] = f2bf(o[ni][j] * rj[j]);
  }
}

// ---------------- output projection + bias, f32 out; 64x64 tiles (768 blocks, 3/CU) ----------------
// flat grid, m-fastest within XCD chunks (B=WpT panel L2-resident).
__global__ __launch_bounds__(256) void gemm_proj(const unsigned short* __restrict__ A,
                                                 const unsigned short* __restrict__ B,
                                                 const float* __restrict__ bias,
                                                 float* __restrict__ C) {
  __shared__ unsigned short As[2][64 * 64], Bs[2][64 * 64];
  const int flat = blockIdx.x;                     // 768 blocks
  const int lid = (flat & 7) * 96 + (flat >> 3);
  const int m0 = (lid & 63) * 64;                  // m fastest within chunk
  const int n0 = (lid >> 6) * 64;
  const int t = threadIdx.x, l = t & 63, wid = t >> 6;
  const int g = l >> 4, c16 = l & 15;
  const int wm = (wid >> 1) * 32, wn = (wid & 1) * 32;
  auto stage = [&](unsigned short* dst, const unsigned short* src, int base, int k0) {
#pragma unroll
    for (int i = 0; i < 2; ++i) {
      int fc = i * 256 + t, r = fc >> 3, c = (fc & 7) ^ ((r >> 1) & 7);
      gload_lds16(src + (size_t)(base + r) * 768 + k0 + c * 8, (char*)dst + fc * 16);
    }
  };
  stage(As[0], A, m0, 0);
  stage(Bs[0], B, n0, 0);
  asm volatile("s_waitcnt vmcnt(0)" ::: "memory");
  __syncthreads();
  f32x4 acc[2][2] = {};
  for (int s = 0; s < 12; ++s) {
    const int cur = s & 1;
    if (s < 11) {
      stage(As[cur ^ 1], A, m0, (s + 1) * 64);
      stage(Bs[cur ^ 1], B, n0, (s + 1) * 64);
    }
#pragma unroll
    for (int kk = 0; kk < 2; ++kk) {
      const int ch = kk * 4 + g;
      bf16x8 a[2], bw[2];
#pragma unroll
      for (int mi = 0; mi < 2; ++mi) {
        int r = wm + mi * 16 + c16;
        a[mi] = *(const bf16x8*)((char*)As[cur] + r * 128 + (((ch ^ (r >> 1)) & 7) << 4));
      }
#pragma unroll
      for (int ni = 0; ni < 2; ++ni) {
        int r = wn + ni * 16 + c16;
        bw[ni] = *(const bf16x8*)((char*)Bs[cur] + r * 128 + (((ch ^ (r >> 1)) & 7) << 4));
      }
#pragma unroll
      for (int mi = 0; mi < 2; ++mi)
#pragma unroll
        for (int ni = 0; ni < 2; ++ni)
          acc[mi][ni] = mfma16(a[mi], bw[ni], acc[mi][ni]);
    }
    __syncthreads();
  }
#pragma unroll
  for (int mi = 0; mi < 2; ++mi)
#pragma unroll
    for (int ni = 0; ni < 2; ++ni) {
      int col = n0 + wn + ni * 16 + c16;
      int row = m0 + wm + mi * 16 + g * 4;
      float bv = bias[col];
#pragma unroll
      for (int j = 0; j < 4; ++j)
        C[(size_t)(row + j) * 768 + col] = acc[mi][ni][j] + bv;
    }
}

extern "C" void kernel_launch(void* const* d_in, const int* in_sizes, int n_in,
                              void* d_out, int out_size, void* d_ws, size_t ws_size,
                              hipStream_t stream) {
  const float* q    = (const float*)d_in[0];
  const float* k    = (const float*)d_in[1];
  const float* v    = (const float*)d_in[2];
  const float* mask = (const float*)d_in[3];
  const float* Wq   = (const float*)d_in[4];
  const float* Wk   = (const float*)d_in[5];
  const float* Wv   = (const float*)d_in[6];
  const float* Wp   = (const float*)d_in[7];
  const float* bp   = (const float*)d_in[8];
  float* out = (float*)d_out;

  const size_t MN = (size_t)4096 * 768;   // tokens x channels
  const size_t WW = (size_t)768 * 768;
  unsigned short* qkv_bf = (unsigned short*)d_ws;       // 3*MN
  unsigned short* wt     = qkv_bf + 3 * MN;             // 4*WW (WqT,WkT,WvT,WpT)
  unsigned short* heads  = wt + 4 * WW;                 // qh | kh | vhT, 3*MN
  unsigned short* xb     = heads + 3 * MN;              // attention out, MN

  conv_all<<<dim3(3072, 4), 256, 0, stream>>>(q, k, v, Wq, Wk, Wv, Wp, qkv_bf, wt);
  gemm_qkv<<<dim3(576), 256, 0, stream>>>(qkv_bf, wt, heads, heads + MN, heads + 2 * MN);
  attn<<<dim3(768), 256, 0, stream>>>(heads, heads + MN, heads + 2 * MN, mask, xb);
  gemm_proj<<<dim3(768), 256, 0, stream>>>(xb, wt + 3 * WW, bp, out);
}

// Round 20
// 92.614 us; speedup vs baseline: 1.0206x; 1.0206x over previous
//
#include <hip/hip_runtime.h>

typedef __bf16 bf16x8 __attribute__((ext_vector_type(8)));
typedef float f32x4 __attribute__((ext_vector_type(4)));

__device__ __forceinline__ unsigned short f2bf(float f) {
  union { float f; unsigned u; } x; x.f = f;
  unsigned r = x.u + 0x7FFFu + ((x.u >> 16) & 1u);
  return (unsigned short)(r >> 16);
}

// raw v_exp_f32 (2^x) — skips libm's denormal-guard sequence; inputs bounded here.
__device__ __forceinline__ float fast_exp2(float x) {
  float r;
  asm("v_exp_f32 %0, %1" : "=v"(r) : "v"(x));
  return r;
}

// async global->LDS, 16B per lane; LDS dest must be linear (base + lane*16).
__device__ __forceinline__ void gload_lds16(const void* g, void* l) {
  __builtin_amdgcn_global_load_lds(
      (const __attribute__((address_space(1))) unsigned int*)g,
      (__attribute__((address_space(3))) unsigned int*)l, 16, 0, 0);
}

__device__ __forceinline__ f32x4 mfma16(bf16x8 a, bf16x8 b, f32x4 c) {
  return __builtin_amdgcn_mfma_f32_16x16x32_bf16(a, b, c, 0, 0, 0);
}

__device__ __forceinline__ bf16x8 pack8(const f32x4& a, const f32x4& b) {
  bf16x8 r;
  r[0] = (__bf16)a[0]; r[1] = (__bf16)a[1]; r[2] = (__bf16)a[2]; r[3] = (__bf16)a[3];
  r[4] = (__bf16)b[0]; r[5] = (__bf16)b[1]; r[6] = (__bf16)b[2]; r[7] = (__bf16)b[3];
  return r;
}

// ---------------- fused conversions: y<3 -> q/k/v f32->bf16; y==3 -> W transpose ----------------
// Kept as a separate pass: fusing the A-conversion into gemm_qkv (r17) raised FETCH 24->72MB
// (f32 A re-read 6x no longer L2-fits) and dropped occupancy to 12% — 57MB once is cheaper.
__global__ __launch_bounds__(256) void conv_all(const float* __restrict__ q,
                                                const float* __restrict__ k,
                                                const float* __restrict__ v,
                                                const float* __restrict__ W0,
                                                const float* __restrict__ W1,
                                                const float* __restrict__ W2,
                                                const float* __restrict__ W3,
                                                unsigned short* __restrict__ dst,
                                                unsigned short* __restrict__ Wt) {
  __shared__ float tile[32][33];
  if (blockIdx.y < 3) {
    const float* src = (blockIdx.y == 0) ? q : (blockIdx.y == 1 ? k : v);
    size_t i = ((size_t)blockIdx.x * 256 + threadIdx.x) * 4;
    float4 f = *(const float4*)(src + i);
    ushort4 u;
    u.x = f2bf(f.x); u.y = f2bf(f.y); u.z = f2bf(f.z); u.w = f2bf(f.w);
    *(ushort4*)(dst + (size_t)blockIdx.y * (4096u * 768u) + i) = u;
  } else {
    if (blockIdx.x >= 2304) return;   // 24*24*4 W-transpose blocks
    int idx = blockIdx.x;
    int bx = idx % 24, by = (idx / 24) % 24, bz = idx / 576;
    const float* W = (bz == 0) ? W0 : (bz == 1) ? W1 : (bz == 2) ? W2 : W3;
    int tx = threadIdx.x & 31, ty = threadIdx.x >> 5;  // 32 x 8
    int n0 = bx * 32, k0 = by * 32;
#pragma unroll
    for (int i = 0; i < 4; ++i)
      tile[ty * 4 + i][tx] = W[(size_t)(k0 + ty * 4 + i) * 768 + n0 + tx];
    __syncthreads();
    unsigned short* o = Wt + (size_t)bz * 768 * 768;
#pragma unroll
    for (int i = 0; i < 4; ++i)
      o[(size_t)(n0 + ty * 4 + i) * 768 + k0 + tx] = f2bf(tile[tx][ty * 4 + i]);
  }
}

// ---------------- QKV projections: 128x128 tile, 4 waves, dbuf BK=64 ----------------
// (z=0 qh*SCALE*log2e, z=1 kh, z=2 vh-transposed)
// flat grid, m-fastest within XCD chunks: B panel stays L2-resident per XCD.
__global__ __launch_bounds__(256) void gemm_qkv(const unsigned short* __restrict__ Abase,
                                                const unsigned short* __restrict__ Wt,
                                                unsigned short* __restrict__ Hq,
                                                unsigned short* __restrict__ Hk,
                                                unsigned short* __restrict__ Hvt) {
  __shared__ unsigned short As[2][128 * 64], Bs[2][128 * 64];  // 64 KB
  const int flat = blockIdx.x;                    // 576 blocks
  const int lid = (flat & 7) * 72 + (flat >> 3);  // XCD k gets lid [k*72,(k+1)*72)
  const int z = lid / 192;
  const int rem = lid - z * 192;
  const int m0 = (rem & 31) * 128;                // m fastest within chunk
  const int n0 = (rem >> 5) * 128;
  const unsigned short* A = Abase + (size_t)z * 4096 * 768;
  const unsigned short* B = Wt + (size_t)z * 768 * 768;
  const int t = threadIdx.x, l = t & 63, wid = t >> 6;
  const int g = l >> 4, c16 = l & 15;
  const int wm = (wid >> 1) * 64, wn = (wid & 1) * 64;

  auto stage = [&](unsigned short* dst, const unsigned short* src, int base, int k0) {
#pragma unroll
    for (int i = 0; i < 4; ++i) {
      int fc = i * 256 + t, r = fc >> 3, c = (fc & 7) ^ ((r >> 1) & 7);
      gload_lds16(src + (size_t)(base + r) * 768 + k0 + c * 8, (char*)dst + fc * 16);
    }
  };
  stage(As[0], A, m0, 0);
  stage(Bs[0], B, n0, 0);
  asm volatile("s_waitcnt vmcnt(0)" ::: "memory");
  __syncthreads();
  f32x4 acc[4][4] = {};
  for (int s = 0; s < 12; ++s) {
    const int cur = s & 1;
    if (s < 11) {
      stage(As[cur ^ 1], A, m0, (s + 1) * 64);
      stage(Bs[cur ^ 1], B, n0, (s + 1) * 64);
    }
#pragma unroll
    for (int kk = 0; kk < 2; ++kk) {
      const int ch = kk * 4 + g;
      bf16x8 a[4], bw[4];
#pragma unroll
      for (int mi = 0; mi < 4; ++mi) {
        int r = wm + mi * 16 + c16;
        a[mi] = *(const bf16x8*)((char*)As[cur] + r * 128 + (((ch ^ (r >> 1)) & 7) << 4));
      }
#pragma unroll
      for (int ni = 0; ni < 4; ++ni) {
        int r = wn + ni * 16 + c16;
        bw[ni] = *(const bf16x8*)((char*)Bs[cur] + r * 128 + (((ch ^ (r >> 1)) & 7) << 4));
      }
#pragma unroll
      for (int mi = 0; mi < 4; ++mi)
#pragma unroll
        for (int ni = 0; ni < 4; ++ni)
          acc[mi][ni] = mfma16(a[mi], bw[ni], acc[mi][ni]);
    }
    __syncthreads();
  }

  if (z < 2) {
    // fold SCALE*log2(e) into q so attn uses exp2 directly
    const float f = (z == 0) ? 0.125f * 1.44269504088896341f : 1.0f;
    unsigned short* C = (z == 0) ? Hq : Hk;
#pragma unroll
    for (int mi = 0; mi < 4; ++mi)
#pragma unroll
      for (int ni = 0; ni < 4; ++ni) {
        int col = n0 + wn + ni * 16 + c16;
        int row = m0 + wm + mi * 16 + g * 4;
#pragma unroll
        for (int j = 0; j < 4; ++j)
          C[(size_t)(row + j) * 768 + col] = f2bf(acc[mi][ni][j] * f);
      }
  } else {
    // vhT[(b*768 + col)*1024 + m] : head-major rows, sequence contiguous
#pragma unroll
    for (int mi = 0; mi < 4; ++mi) {
      int rowbase = m0 + wm + mi * 16;  // 128-tile never crosses the 1024 batch bound
      int bat = rowbase >> 10;
      int mloc = (rowbase & 1023) + g * 4;
#pragma unroll
      for (int ni = 0; ni < 4; ++ni) {
        int col = n0 + wn + ni * 16 + c16;
        ushort4 u;
        u.x = f2bf(acc[mi][ni][0]); u.y = f2bf(acc[mi][ni][1]);
        u.z = f2bf(acc[mi][ni][2]); u.w = f2bf(acc[mi][ni][3]);
        *(ushort4*)(Hvt + (((size_t)(bat * 768 + col)) << 10) + mloc) = u;
      }
    }
  }
}

// ---------------- fused attention: FINAL (39.6-40.3us measured). swapped QK^T,
//   sigma-permuted K rows, 3-buf KVBLK=64, fast_exp2, vmcnt(4)+s_barrier per iter. ----------------
// Falsified alternatives (all regressed): deeper prefetch (r6/r7/r9), full unroll (r10),
// no-LDS streaming (r8), KVBLK=128 (r13), kv-split x2 (r15), fused f32 staging (r17),
// setprio T5 (r19: -2.5us, no phase diversity to arbitrate).
// K LDS position p holds global kv row sigma(p) = 32*(p>>5) + 8*((p>>2)&3) + 4*((p>>4)&1) + (p&3).
// After mfma(K,Q): lane (g,c16) p[ni][j] = S[q=c16][kv = 32*(ni>>1)+8g+4*(ni&1)+j] ->
// post-softmax values ARE the PV A-fragments. No P LDS round-trip.
__global__ __launch_bounds__(256) void attn(const unsigned short* __restrict__ qh,
                                            const unsigned short* __restrict__ kh,
                                            const unsigned short* __restrict__ vhT,
                                            const float* __restrict__ mask,
                                            unsigned short* __restrict__ xb) {
  __shared__ unsigned short Ks[3][64 * 64], Vts[3][64 * 64];
  // h-fastest order + XCD-chunk swizzle: XCD k gets one batch's K/V (L2-fits) and
  // co-residents the 12 h-blocks sharing each mask tile.
  const int flat = blockIdx.x;                    // 768 blocks
  const int lid = (flat & 7) * 96 + (flat >> 3);  // dispatch i -> XCD i%8
  const int h = lid % 12, qt = (lid / 12) & 15, b = lid / 192;
  const int t = threadIdx.x, l = t & 63, wid = t >> 6;
  const int g = l >> 4, c16 = l & 15;

  // Q B-fragments straight to registers (q-col = qt*64+wid*16+c16, chans kk*32+g*8..+8)
  const unsigned short* qp =
      qh + ((size_t)(b * 1024 + qt * 64 + wid * 16 + c16)) * 768 + h * 64 + g * 8;
  bf16x8 aq0 = *(const bf16x8*)qp;
  bf16x8 aq1 = *(const bf16x8*)(qp + 32);

  // per-lane staging source pointers; K rows sigma-permuted, V linear
  const int fc0 = t, r0 = fc0 >> 3, c0 = (fc0 & 7) ^ ((r0 >> 1) & 7);
  const int fc1 = 256 + t, r1 = fc1 >> 3, c1 = (fc1 & 7) ^ ((r1 >> 1) & 7);
  const int s0 = 32 * (r0 >> 5) + 8 * ((r0 >> 2) & 3) + 4 * ((r0 >> 4) & 1) + (r0 & 3);
  const int s1 = 32 * (r1 >> 5) + 8 * ((r1 >> 2) & 3) + 4 * ((r1 >> 4) & 1) + (r1 & 3);
  const unsigned short* kp0 = kh + (size_t)(b * 1024 + s0) * 768 + h * 64 + c0 * 8;
  const unsigned short* kp1 = kh + (size_t)(b * 1024 + s1) * 768 + h * 64 + c1 * 8;
  const unsigned short* vp0 = vhT + ((size_t)(b * 768 + h * 64 + r0)) * 1024 + c0 * 8;
  const unsigned short* vp1 = vhT + ((size_t)(b * 768 + h * 64 + r1)) * 1024 + c1 * 8;

  auto stageKV = [&](int buf) {
    char* kd = (char*)Ks[buf];
    char* vd = (char*)Vts[buf];
    gload_lds16(kp0, kd + fc0 * 16);
    gload_lds16(kp1, kd + fc1 * 16);
    gload_lds16(vp0, vd + fc0 * 16);
    gload_lds16(vp1, vd + fc1 * 16);
    kp0 += 64 * 768; kp1 += 64 * 768; vp0 += 64; vp1 += 64;
  };

  // mask row base: q-row = c16 (swapped layout), 4-contiguous kv per lane -> float4
  const float* mq = mask + ((size_t)(b * 1024 + qt * 64 + wid * 16 + c16)) * 1024 + 8 * g;

  // prologue: 2 tiles in flight, wait only tile 0
  stageKV(0);
  stageKV(1);
  asm volatile("s_waitcnt vmcnt(4)" ::: "memory");
  __builtin_amdgcn_s_barrier();

  f32x4 o[4] = {};
  f32x4 ls = {0.f, 0.f, 0.f, 0.f};

  for (int kv = 0; kv < 16; ++kv) {
    const int cur = kv % 3;
    if (kv < 14) stageKV((kv + 2) % 3);  // 2-deep prefetch
    // mask tile -> registers, vectorized (latency hides under QK^T)
    const float* mk = mq + kv * 64;
    f32x4 mreg[4];
    mreg[0] = *(const f32x4*)(mk);
    mreg[1] = *(const f32x4*)(mk + 4);
    mreg[2] = *(const f32x4*)(mk + 32);
    mreg[3] = *(const f32x4*)(mk + 36);
    // S^T tiles: mfma(A=K, B=Q) -> lane holds q-row c16
    f32x4 p[4] = {};
#pragma unroll
    for (int kk = 0; kk < 2; ++kk) {
      const int ch = kk * 4 + g;
      bf16x8 aq = kk ? aq1 : aq0;
#pragma unroll
      for (int ni = 0; ni < 4; ++ni) {
        int r = ni * 16 + c16;
        bf16x8 bk = *(const bf16x8*)((char*)Ks[cur] + r * 128 + (((ch ^ (r >> 1)) & 7) << 4));
        p[ni] = mfma16(bk, aq, p[ni]);
      }
    }
    // exp2 via raw v_exp_f32 (q pre-scaled), lane-local row-sum, post-softmax mask
#pragma unroll
    for (int ni = 0; ni < 4; ++ni) {
      float e0 = fast_exp2(p[ni][0]);
      float e1 = fast_exp2(p[ni][1]);
      float e2 = fast_exp2(p[ni][2]);
      float e3 = fast_exp2(p[ni][3]);
      ls[ni] += (e0 + e1) + (e2 + e3);
      p[ni][0] = e0 * mreg[ni][0];
      p[ni][1] = e1 * mreg[ni][1];
      p[ni][2] = e2 * mreg[ni][2];
      p[ni][3] = e3 * mreg[ni][3];
    }
    // P is already in PV A-fragment layout: pack to bf16 and multiply
    bf16x8 pa0 = pack8(p[0], p[1]);  // kv 8g..8g+7
    bf16x8 pa1 = pack8(p[2], p[3]);  // kv 32+8g..+7
#pragma unroll
    for (int kk = 0; kk < 2; ++kk) {
      const int ch = kk * 4 + g;
      bf16x8 ap = kk ? pa1 : pa0;
#pragma unroll
      for (int ni = 0; ni < 4; ++ni) {
        int r = ni * 16 + c16;
        bf16x8 bv = *(const bf16x8*)((char*)Vts[cur] + r * 128 + (((ch ^ (r >> 1)) & 7) << 4));
        o[ni] = mfma16(ap, bv, o[ni]);
      }
    }
    // counted wait: tile kv+1 landed, tile kv+2 may stay in flight (never drain to 0)
    if (kv < 14) {
      asm volatile("s_waitcnt vmcnt(4)" ::: "memory");
      __builtin_amdgcn_s_barrier();
    } else if (kv == 14) {
      asm volatile("s_waitcnt vmcnt(0)" ::: "memory");
      __builtin_amdgcn_s_barrier();
    }
  }
  // full row-sum for q-row c16 lives across lanes c16, c16+16, c16+32, c16+48
  float s = (ls[0] + ls[1]) + (ls[2] + ls[3]);
  s += __shfl_xor(s, 16);
  s += __shfl_xor(s, 32);
  float rinv = 1.0f / s;
  // o rows are q = g*4+j -> fetch that row's rinv (held at lanes with lane&15 == row)
  const int rb = (l & 48) | ((l >> 2) & 12);
  float rj[4];
#pragma unroll
  for (int j = 0; j < 4; ++j) rj[j] = __shfl(rinv, rb + j);
#pragma unroll
  for (int ni = 0; ni < 4; ++ni) {
    int col = h * 64 + ni * 16 + c16;
    int row = qt * 64 + wid * 16 + g * 4;
#pragma unroll
    for (int j = 0; j < 4; ++j)
      xb[((size_t)(b * 1024) + row + j) * 768 + col] = f2bf(o[ni][j] * rj[j]);
  }
}

// ---------------- output projection + bias, f32 out; 64x64 tiles (768 blocks, 3/CU) ----------------
// flat grid, m-fastest within XCD chunks (B=WpT panel L2-resident).
__global__ __launch_bounds__(256) void gemm_proj(const unsigned short* __restrict__ A,
                                                 const unsigned short* __restrict__ B,
                                                 const float* __restrict__ bias,
                                                 float* __restrict__ C) {
  __shared__ unsigned short As[2][64 * 64], Bs[2][64 * 64];
  const int flat = blockIdx.x;                     // 768 blocks
  const int lid = (flat & 7) * 96 + (flat >> 3);
  const int m0 = (lid & 63) * 64;                  // m fastest within chunk
  const int n0 = (lid >> 6) * 64;
  const int t = threadIdx.x, l = t & 63, wid = t >> 6;
  const int g = l >> 4, c16 = l & 15;
  const int wm = (wid >> 1) * 32, wn = (wid & 1) * 32;
  auto stage = [&](unsigned short* dst, const unsigned short* src, int base, int k0) {
#pragma unroll
    for (int i = 0; i < 2; ++i) {
      int fc = i * 256 + t, r = fc >> 3, c = (fc & 7) ^ ((r >> 1) & 7);
      gload_lds16(src + (size_t)(base + r) * 768 + k0 + c * 8, (char*)dst + fc * 16);
    }
  };
  stage(As[0], A, m0, 0);
  stage(Bs[0], B, n0, 0);
  asm volatile("s_waitcnt vmcnt(0)" ::: "memory");
  __syncthreads();
  f32x4 acc[2][2] = {};
  for (int s = 0; s < 12; ++s) {
    const int cur = s & 1;
    if (s < 11) {
      stage(As[cur ^ 1], A, m0, (s + 1) * 64);
      stage(Bs[cur ^ 1], B, n0, (s + 1) * 64);
    }
#pragma unroll
    for (int kk = 0; kk < 2; ++kk) {
      const int ch = kk * 4 + g;
      bf16x8 a[2], bw[2];
#pragma unroll
      for (int mi = 0; mi < 2; ++mi) {
        int r = wm + mi * 16 + c16;
        a[mi] = *(const bf16x8*)((char*)As[cur] + r * 128 + (((ch ^ (r >> 1)) & 7) << 4));
      }
#pragma unroll
      for (int ni = 0; ni < 2; ++ni) {
        int r = wn + ni * 16 + c16;
        bw[ni] = *(const bf16x8*)((char*)Bs[cur] + r * 128 + (((ch ^ (r >> 1)) & 7) << 4));
      }
#pragma unroll
      for (int mi = 0; mi < 2; ++mi)
#pragma unroll
        for (int ni = 0; ni < 2; ++ni)
          acc[mi][ni] = mfma16(a[mi], bw[ni], acc[mi][ni]);
    }
    __syncthreads();
  }
#pragma unroll
  for (int mi = 0; mi < 2; ++mi)
#pragma unroll
    for (int ni = 0; ni < 2; ++ni) {
      int col = n0 + wn + ni * 16 + c16;
      int row = m0 + wm + mi * 16 + g * 4;
      float bv = bias[col];
#pragma unroll
      for (int j = 0; j < 4; ++j)
        C[(size_t)(row + j) * 768 + col] = acc[mi][ni][j] + bv;
    }
}

extern "C" void kernel_launch(void* const* d_in, const int* in_sizes, int n_in,
                              void* d_out, int out_size, void* d_ws, size_t ws_size,
                              hipStream_t stream) {
  const float* q    = (const float*)d_in[0];
  const float* k    = (const float*)d_in[1];
  const float* v    = (const float*)d_in[2];
  const float* mask = (const float*)d_in[3];
  const float* Wq   = (const float*)d_in[4];
  const float* Wk   = (const float*)d_in[5];
  const float* Wv   = (const float*)d_in[6];
  const float* Wp   = (const float*)d_in[7];
  const float* bp   = (const float*)d_in[8];
  float* out = (float*)d_out;

  const size_t MN = (size_t)4096 * 768;   // tokens x channels
  const size_t WW = (size_t)768 * 768;
  unsigned short* qkv_bf = (unsigned short*)d_ws;       // 3*MN
  unsigned short* wt     = qkv_bf + 3 * MN;             // 4*WW (WqT,WkT,WvT,WpT)
  unsigned short* heads  = wt + 4 * WW;                 // qh | kh | vhT, 3*MN
  unsigned short* xb     = heads + 3 * MN;              // attention out, MN

  conv_all<<<dim3(3072, 4), 256, 0, stream>>>(q, k, v, Wq, Wk, Wv, Wp, qkv_bf, wt);
  gemm_qkv<<<dim3(576), 256, 0, stream>>>(qkv_bf, wt, heads, heads + MN, heads + 2 * MN);
  attn<<<dim3(768), 256, 0, stream>>>(heads, heads + MN, heads + 2 * MN, mask, xb);
  gemm_proj<<<dim3(768), 256, 0, stream>>>(xb, wt + 3 * WW, bp, out);
}